// Round 5
// baseline (2885.200 us; speedup 1.0000x reference)
//
#include <hip/hip_runtime.h>
#include <math.h>

#define HD __host__ __device__

static constexpr int NNODE = 30000;   // nodes
static constexpr int HH    = 512;     // HEADS*HID = hidden width (both layers)
static constexpr int HEADS = 8;
static constexpr int CD    = 64;      // channels per head (HID and NUM_CLASSES)
static constexpr float SLOPE = 0.2f;

// ---------------- threefry2x32 (exact JAX semantics) ----------------
HD inline unsigned rotl32(unsigned v, int s){ return (v<<s) | (v>>(32-s)); }

HD inline void tf2x32(unsigned k0, unsigned k1, unsigned c0, unsigned c1,
                      unsigned &o0, unsigned &o1){
  unsigned ks2 = k0 ^ k1 ^ 0x1BD11BDAu;
  unsigned x0 = c0 + k0, x1 = c1 + k1;
  // 5 groups of 4 rounds; rot sets A=[13,15,26,6], B=[17,29,16,24]
  x0+=x1; x1=rotl32(x1,13); x1^=x0;
  x0+=x1; x1=rotl32(x1,15); x1^=x0;
  x0+=x1; x1=rotl32(x1,26); x1^=x0;
  x0+=x1; x1=rotl32(x1, 6); x1^=x0;
  x0 += k1; x1 += ks2 + 1u;
  x0+=x1; x1=rotl32(x1,17); x1^=x0;
  x0+=x1; x1=rotl32(x1,29); x1^=x0;
  x0+=x1; x1=rotl32(x1,16); x1^=x0;
  x0+=x1; x1=rotl32(x1,24); x1^=x0;
  x0 += ks2; x1 += k0 + 2u;
  x0+=x1; x1=rotl32(x1,13); x1^=x0;
  x0+=x1; x1=rotl32(x1,15); x1^=x0;
  x0+=x1; x1=rotl32(x1,26); x1^=x0;
  x0+=x1; x1=rotl32(x1, 6); x1^=x0;
  x0 += k0; x1 += k1 + 3u;
  x0+=x1; x1=rotl32(x1,17); x1^=x0;
  x0+=x1; x1=rotl32(x1,29); x1^=x0;
  x0+=x1; x1=rotl32(x1,16); x1^=x0;
  x0+=x1; x1=rotl32(x1,24); x1^=x0;
  x0 += k1; x1 += ks2 + 4u;
  x0+=x1; x1=rotl32(x1,13); x1^=x0;
  x0+=x1; x1=rotl32(x1,15); x1^=x0;
  x0+=x1; x1=rotl32(x1,26); x1^=x0;
  x0+=x1; x1=rotl32(x1, 6); x1^=x0;
  x0 += ks2; x1 += k0 + 5u;
  o0 = x0; o1 = x1;
}

// ---------------- fused dropout + (optional bias) + ELU ----------------
// jax_threefry_partitionable=True semantics:
//   bits[i] = o0 ^ o1 where (o0,o1) = threefry(key, (hi32(i), lo32(i))) = tf(key,(0,i))
__global__ void dropelu_kernel(const float* __restrict__ in, const float* __restrict__ bias,
                               float* __restrict__ out,
                               unsigned key0, unsigned key1, int total, int width){
  int i = blockIdx.x * blockDim.x + threadIdx.x;
  if (i >= total) return;
  unsigned o0, o1;
  tf2x32(key0, key1, 0u, (unsigned)i, o0, o1);
  unsigned bits = o0 ^ o1;
  float u = __uint_as_float((bits >> 9) | 0x3f800000u) - 1.0f;  // [0,1)
  float v = in[i];
  if (bias) v += bias[i % width];
  v = (u < 0.8f) ? (v / 0.8f) : 0.0f;          // dropout keep-prob 0.8
  out[i] = (v > 0.0f) ? v : expm1f(v);         // ELU (alpha=1)
}

// ---------------- f32 GEMM: C[M,512] = A[M,512] @ B[512,512] ----------------
#define BM 128
#define BN 128
#define BK 16
__global__ __launch_bounds__(256) void gemm_f32_kernel(const float* __restrict__ A,
                                                       const float* __restrict__ B,
                                                       float* __restrict__ C, int M){
  constexpr int K = 512, NCOLS = 512;
  __shared__ float As[BK][BM];   // transposed A tile
  __shared__ float Bs[BK][BN];
  int t  = threadIdx.x;
  int bx = blockIdx.x % (NCOLS / BN);
  int by = blockIdx.x / (NCOLS / BN);
  int row0 = by * BM, col0 = bx * BN;
  int tx = t & 15, ty = t >> 4;
  float acc[8][8] = {};
  for (int k0 = 0; k0 < K; k0 += BK){
    #pragma unroll
    for (int l = 0; l < 2; ++l){            // A tile: 512 float4
      int idx = t + l * 256;
      int r = idx >> 2, c4 = idx & 3;
      float4 v = make_float4(0.f,0.f,0.f,0.f);
      int gr = row0 + r;
      if (gr < M) v = *reinterpret_cast<const float4*>(&A[gr * K + k0 + c4 * 4]);
      As[c4*4+0][r] = v.x; As[c4*4+1][r] = v.y; As[c4*4+2][r] = v.z; As[c4*4+3][r] = v.w;
    }
    #pragma unroll
    for (int l = 0; l < 2; ++l){            // B tile: 512 float4
      int idx = t + l * 256;
      int r = idx >> 5, c4 = idx & 31;
      float4 v = *reinterpret_cast<const float4*>(&B[(k0 + r) * NCOLS + col0 + c4 * 4]);
      *reinterpret_cast<float4*>(&Bs[r][c4 * 4]) = v;
    }
    __syncthreads();
    #pragma unroll
    for (int kk = 0; kk < BK; ++kk){
      float a[8], b[8];
      *reinterpret_cast<float4*>(a)     = *reinterpret_cast<const float4*>(&As[kk][ty*4]);
      *reinterpret_cast<float4*>(a + 4) = *reinterpret_cast<const float4*>(&As[kk][ty*4 + 64]);
      *reinterpret_cast<float4*>(b)     = *reinterpret_cast<const float4*>(&Bs[kk][tx*4]);
      *reinterpret_cast<float4*>(b + 4) = *reinterpret_cast<const float4*>(&Bs[kk][tx*4 + 64]);
      #pragma unroll
      for (int i = 0; i < 8; ++i)
        #pragma unroll
        for (int j = 0; j < 8; ++j)
          acc[i][j] += a[i] * b[j];
    }
    __syncthreads();
  }
  #pragma unroll
  for (int i = 0; i < 8; ++i){
    int gr = row0 + ((i < 4) ? (ty*4 + i) : (ty*4 + 64 + (i - 4)));
    if (gr >= M) continue;
    float4 v0 = make_float4(acc[i][0], acc[i][1], acc[i][2], acc[i][3]);
    float4 v1 = make_float4(acc[i][4], acc[i][5], acc[i][6], acc[i][7]);
    *reinterpret_cast<float4*>(&C[gr * NCOLS + col0 + tx*4])      = v0;
    *reinterpret_cast<float4*>(&C[gr * NCOLS + col0 + tx*4 + 64]) = v1;
  }
}

// ---------------- attention coefficients: a_s/a_d [N, HEADS] ----------------
__global__ void attn_coef_kernel(const float* __restrict__ xp, const float* __restrict__ att_src,
                                 const float* __restrict__ att_dst,
                                 float* __restrict__ a_s, float* __restrict__ a_d){
  int wid = (blockIdx.x * blockDim.x + threadIdx.x) >> 6;
  int lane = threadIdx.x & 63;
  if (wid >= NNODE * HEADS) return;
  int n = wid >> 3, h = wid & 7;
  float x  = xp[n * HH + h * CD + lane];
  float vs = x * att_src[h * CD + lane];
  float vd = x * att_dst[h * CD + lane];
  #pragma unroll
  for (int off = 32; off; off >>= 1){
    vs += __shfl_xor(vs, off, 64);
    vd += __shfl_xor(vd, off, 64);
  }
  if (lane == 0){ a_s[wid] = vs; a_d[wid] = vd; }
}

// ---------------- monotone float<->uint flip for atomicMax ----------------
__device__ inline unsigned flipf(float f){
  unsigned u = __float_as_uint(f);
  return u ^ (unsigned)(((int)u >> 31) | 0x80000000);
}
__device__ inline float unflipf(unsigned u){
  unsigned v = (u >> 31) ? (u ^ 0x80000000u) : ~u;
  return __uint_as_float(v);
}

__device__ inline void edge_endpoints(const int* __restrict__ ei, int t, int E, int& src, int& dst){
  if (t < E){ src = ei[t]; dst = ei[E + t]; }
  else      { src = t - E; dst = t - E; }      // self loops
}

__global__ void edge_max_kernel(const int* __restrict__ ei, const float* __restrict__ a_s,
                                const float* __restrict__ a_d, unsigned* __restrict__ mflip, int E){
  int idx = blockIdx.x * blockDim.x + threadIdx.x;
  int total = (E + NNODE) * HEADS;
  if (idx >= total) return;
  int t = idx >> 3, h = idx & 7;
  int src, dst; edge_endpoints(ei, t, E, src, dst);
  float e = a_s[src * 8 + h] + a_d[dst * 8 + h];
  e = (e >= 0.f) ? e : SLOPE * e;
  atomicMax(&mflip[dst * 8 + h], flipf(e));
}

__global__ void edge_sum_kernel(const int* __restrict__ ei, const float* __restrict__ a_s,
                                const float* __restrict__ a_d, const unsigned* __restrict__ mflip,
                                float* __restrict__ ssum, int E){
  int idx = blockIdx.x * blockDim.x + threadIdx.x;
  int total = (E + NNODE) * HEADS;
  if (idx >= total) return;
  int t = idx >> 3, h = idx & 7;
  int src, dst; edge_endpoints(ei, t, E, src, dst);
  float e = a_s[src * 8 + h] + a_d[dst * 8 + h];
  e = (e >= 0.f) ? e : SLOPE * e;
  float m = unflipf(mflip[dst * 8 + h]);
  atomicAdd(&ssum[dst * 8 + h], expf(e - m));
}

template <bool CONCAT>
__global__ void edge_msg_kernel(const int* __restrict__ ei, const float* __restrict__ a_s,
                                const float* __restrict__ a_d, const unsigned* __restrict__ mflip,
                                const float* __restrict__ ssum, const float* __restrict__ xp,
                                float* __restrict__ out, int E){
  int wid  = (blockIdx.x * blockDim.x + threadIdx.x) >> 6;   // one wave per (edge, head)
  int lane = threadIdx.x & 63;
  int total = (E + NNODE) * HEADS;
  if (wid >= total) return;
  int t = wid >> 3, h = wid & 7;
  int src, dst; edge_endpoints(ei, t, E, src, dst);
  float e = a_s[src * 8 + h] + a_d[dst * 8 + h];
  e = (e >= 0.f) ? e : SLOPE * e;
  float m = unflipf(mflip[dst * 8 + h]);
  float p = expf(e - m);
  float alpha = p / (ssum[dst * 8 + h] + 1e-16f);
  float v = xp[src * HH + h * CD + lane];
  if (CONCAT) atomicAdd(&out[dst * HH + h * CD + lane], alpha * v);
  else        atomicAdd(&out[dst * CD + lane], 0.125f * alpha * v);
}

__global__ void bias_add_kernel(float* __restrict__ out, const float* __restrict__ b,
                                int size, int width){
  int i = blockIdx.x * blockDim.x + threadIdx.x;
  if (i < size) out[i] += b[i % width];
}

// ---------------- host launch ----------------
extern "C" void kernel_launch(void* const* d_in, const int* in_sizes, int n_in,
                              void* d_out, int out_size, void* d_ws, size_t ws_size,
                              hipStream_t stream){
  const float* x   = (const float*)d_in[0];
  const int*   ei  = (const int*)  d_in[1];   // int32 (JAX x64 disabled downcasts int64)
  const float* W1  = (const float*)d_in[2];
  const float* as1 = (const float*)d_in[3];
  const float* ad1 = (const float*)d_in[4];
  const float* b1  = (const float*)d_in[5];
  const float* W2  = (const float*)d_in[6];
  const float* as2 = (const float*)d_in[7];
  const float* ad2 = (const float*)d_in[8];
  const float* b2  = (const float*)d_in[9];
  float* out = (float*)d_out;
  const int E = in_sizes[1] / 2;

  // workspace carve-up
  char* w = (char*)d_ws;
  float* hbuf = (float*)w; w += (size_t)NNODE * HH * 4;   // 61.44 MB
  float* xp   = (float*)w; w += (size_t)NNODE * HH * 4;   // 61.44 MB
  float* o1   = (float*)w; w += (size_t)NNODE * HH * 4;   // 61.44 MB
  float* a_s  = (float*)w; w += (size_t)NNODE * HEADS * 4;
  float* a_d  = (float*)w; w += (size_t)NNODE * HEADS * 4;
  unsigned* mflip = (unsigned*)w; w += (size_t)NNODE * HEADS * 4;
  float* ssum = (float*)w; w += (size_t)NNODE * HEADS * 4;

  // partitionable (fold-like) split of jax.random.key(42) = (0,42):
  //   child j = full threefry output with counter (0, j)
  unsigned k1a, k1b, k2a, k2b;
  tf2x32(0u, 42u, 0u, 0u, k1a, k1b);   // k1
  tf2x32(0u, 42u, 0u, 1u, k2a, k2b);   // k2

  const int total = NNODE * HH;                    // 15,360,000
  const int etot = (E + NNODE) * HEADS;            // 4,080,000
  const int gemm_grid = ((NNODE + BM - 1) / BM) * (512 / BN);

  // ---- layer 1 ----
  dropelu_kernel<<<(total + 255) / 256, 256, 0, stream>>>(x, nullptr, hbuf, k1a, k1b, total, HH);
  gemm_f32_kernel<<<gemm_grid, 256, 0, stream>>>(hbuf, W1, xp, NNODE);
  attn_coef_kernel<<<(NNODE * HEADS + 3) / 4, 256, 0, stream>>>(xp, as1, ad1, a_s, a_d);
  hipMemsetAsync(mflip, 0, (size_t)NNODE * HEADS * 4, stream);
  hipMemsetAsync(ssum,  0, (size_t)NNODE * HEADS * 4, stream);
  hipMemsetAsync(o1,    0, (size_t)NNODE * HH * 4, stream);
  edge_max_kernel<<<(etot + 255) / 256, 256, 0, stream>>>(ei, a_s, a_d, mflip, E);
  edge_sum_kernel<<<(etot + 255) / 256, 256, 0, stream>>>(ei, a_s, a_d, mflip, ssum, E);
  edge_msg_kernel<true><<<(etot + 3) / 4, 256, 0, stream>>>(ei, a_s, a_d, mflip, ssum, xp, o1, E);

  // ---- layer 2 ----
  dropelu_kernel<<<(total + 255) / 256, 256, 0, stream>>>(o1, b1, hbuf, k2a, k2b, total, HH);
  gemm_f32_kernel<<<gemm_grid, 256, 0, stream>>>(hbuf, W2, xp, NNODE);
  attn_coef_kernel<<<(NNODE * HEADS + 3) / 4, 256, 0, stream>>>(xp, as2, ad2, a_s, a_d);
  hipMemsetAsync(mflip, 0, (size_t)NNODE * HEADS * 4, stream);
  hipMemsetAsync(ssum,  0, (size_t)NNODE * HEADS * 4, stream);
  hipMemsetAsync(out,   0, (size_t)NNODE * CD * 4, stream);
  edge_max_kernel<<<(etot + 255) / 256, 256, 0, stream>>>(ei, a_s, a_d, mflip, E);
  edge_sum_kernel<<<(etot + 255) / 256, 256, 0, stream>>>(ei, a_s, a_d, mflip, ssum, E);
  edge_msg_kernel<false><<<(etot + 3) / 4, 256, 0, stream>>>(ei, a_s, a_d, mflip, ssum, xp, out, E);
  bias_add_kernel<<<(NNODE * CD + 255) / 256, 256, 0, stream>>>(out, b2, NNODE * CD, CD);
}

// Round 6
// 1485.529 us; speedup vs baseline: 1.9422x; 1.9422x over previous
//
#include <hip/hip_runtime.h>
#include <math.h>

#define HD __host__ __device__

static constexpr int NNODE = 30000;   // nodes
static constexpr int HH    = 512;     // HEADS*HID = hidden width (both layers)
static constexpr int HEADS = 8;
static constexpr int CD    = 64;      // channels per head (HID and NUM_CLASSES)
static constexpr float SLOPE = 0.2f;
static constexpr int CHUNK = 128;     // per-wave LDS cache for p/src (deg > CHUNK -> recompute path)

// ---------------- threefry2x32 (exact JAX semantics) ----------------
HD inline unsigned rotl32(unsigned v, int s){ return (v<<s) | (v>>(32-s)); }

HD inline void tf2x32(unsigned k0, unsigned k1, unsigned c0, unsigned c1,
                      unsigned &o0, unsigned &o1){
  unsigned ks2 = k0 ^ k1 ^ 0x1BD11BDAu;
  unsigned x0 = c0 + k0, x1 = c1 + k1;
  x0+=x1; x1=rotl32(x1,13); x1^=x0;
  x0+=x1; x1=rotl32(x1,15); x1^=x0;
  x0+=x1; x1=rotl32(x1,26); x1^=x0;
  x0+=x1; x1=rotl32(x1, 6); x1^=x0;
  x0 += k1; x1 += ks2 + 1u;
  x0+=x1; x1=rotl32(x1,17); x1^=x0;
  x0+=x1; x1=rotl32(x1,29); x1^=x0;
  x0+=x1; x1=rotl32(x1,16); x1^=x0;
  x0+=x1; x1=rotl32(x1,24); x1^=x0;
  x0 += ks2; x1 += k0 + 2u;
  x0+=x1; x1=rotl32(x1,13); x1^=x0;
  x0+=x1; x1=rotl32(x1,15); x1^=x0;
  x0+=x1; x1=rotl32(x1,26); x1^=x0;
  x0+=x1; x1=rotl32(x1, 6); x1^=x0;
  x0 += k0; x1 += k1 + 3u;
  x0+=x1; x1=rotl32(x1,17); x1^=x0;
  x0+=x1; x1=rotl32(x1,29); x1^=x0;
  x0+=x1; x1=rotl32(x1,16); x1^=x0;
  x0+=x1; x1=rotl32(x1,24); x1^=x0;
  x0 += k1; x1 += ks2 + 4u;
  x0+=x1; x1=rotl32(x1,13); x1^=x0;
  x0+=x1; x1=rotl32(x1,15); x1^=x0;
  x0+=x1; x1=rotl32(x1,26); x1^=x0;
  x0+=x1; x1=rotl32(x1, 6); x1^=x0;
  x0 += ks2; x1 += k0 + 5u;
  o0 = x0; o1 = x1;
}

// ---------------- fused dropout + (optional bias) + ELU ----------------
// jax_threefry_partitionable: bits[i] = o0^o1, (o0,o1)=tf(key,(0,i))
__global__ void dropelu_kernel(const float* __restrict__ in, const float* __restrict__ bias,
                               float* __restrict__ out,
                               unsigned key0, unsigned key1, int total, int width){
  int i = blockIdx.x * blockDim.x + threadIdx.x;
  if (i >= total) return;
  unsigned o0, o1;
  tf2x32(key0, key1, 0u, (unsigned)i, o0, o1);
  unsigned bits = o0 ^ o1;
  float u = __uint_as_float((bits >> 9) | 0x3f800000u) - 1.0f;  // [0,1)
  float v = in[i];
  if (bias) v += bias[i % width];
  v = (u < 0.8f) ? (v / 0.8f) : 0.0f;          // dropout keep-prob 0.8
  out[i] = (v > 0.0f) ? v : expm1f(v);         // ELU (alpha=1)
}

// ---------------- f32 GEMM: C[M,512] = A[M,512] @ B[512,512] ----------------
#define BM 128
#define BN 128
#define BK 16
__global__ __launch_bounds__(256) void gemm_f32_kernel(const float* __restrict__ A,
                                                       const float* __restrict__ B,
                                                       float* __restrict__ C, int M){
  constexpr int K = 512, NCOLS = 512;
  __shared__ float As[BK][BM];
  __shared__ float Bs[BK][BN];
  int t  = threadIdx.x;
  int bx = blockIdx.x % (NCOLS / BN);
  int by = blockIdx.x / (NCOLS / BN);
  int row0 = by * BM, col0 = bx * BN;
  int tx = t & 15, ty = t >> 4;
  float acc[8][8] = {};
  for (int k0 = 0; k0 < K; k0 += BK){
    #pragma unroll
    for (int l = 0; l < 2; ++l){
      int idx = t + l * 256;
      int r = idx >> 2, c4 = idx & 3;
      float4 v = make_float4(0.f,0.f,0.f,0.f);
      int gr = row0 + r;
      if (gr < M) v = *reinterpret_cast<const float4*>(&A[gr * K + k0 + c4 * 4]);
      As[c4*4+0][r] = v.x; As[c4*4+1][r] = v.y; As[c4*4+2][r] = v.z; As[c4*4+3][r] = v.w;
    }
    #pragma unroll
    for (int l = 0; l < 2; ++l){
      int idx = t + l * 256;
      int r = idx >> 5, c4 = idx & 31;
      float4 v = *reinterpret_cast<const float4*>(&B[(k0 + r) * NCOLS + col0 + c4 * 4]);
      *reinterpret_cast<float4*>(&Bs[r][c4 * 4]) = v;
    }
    __syncthreads();
    #pragma unroll
    for (int kk = 0; kk < BK; ++kk){
      float a[8], b[8];
      *reinterpret_cast<float4*>(a)     = *reinterpret_cast<const float4*>(&As[kk][ty*4]);
      *reinterpret_cast<float4*>(a + 4) = *reinterpret_cast<const float4*>(&As[kk][ty*4 + 64]);
      *reinterpret_cast<float4*>(b)     = *reinterpret_cast<const float4*>(&Bs[kk][tx*4]);
      *reinterpret_cast<float4*>(b + 4) = *reinterpret_cast<const float4*>(&Bs[kk][tx*4 + 64]);
      #pragma unroll
      for (int i = 0; i < 8; ++i)
        #pragma unroll
        for (int j = 0; j < 8; ++j)
          acc[i][j] += a[i] * b[j];
    }
    __syncthreads();
  }
  #pragma unroll
  for (int i = 0; i < 8; ++i){
    int gr = row0 + ((i < 4) ? (ty*4 + i) : (ty*4 + 64 + (i - 4)));
    if (gr >= M) continue;
    float4 v0 = make_float4(acc[i][0], acc[i][1], acc[i][2], acc[i][3]);
    float4 v1 = make_float4(acc[i][4], acc[i][5], acc[i][6], acc[i][7]);
    *reinterpret_cast<float4*>(&C[gr * NCOLS + col0 + tx*4])      = v0;
    *reinterpret_cast<float4*>(&C[gr * NCOLS + col0 + tx*4 + 64]) = v1;
  }
}

// ---------------- attention coefficients: a_s/a_d [N, HEADS] ----------------
__global__ void attn_coef_kernel(const float* __restrict__ xp, const float* __restrict__ att_src,
                                 const float* __restrict__ att_dst,
                                 float* __restrict__ a_s, float* __restrict__ a_d){
  int wid = (blockIdx.x * blockDim.x + threadIdx.x) >> 6;
  int lane = threadIdx.x & 63;
  if (wid >= NNODE * HEADS) return;
  int n = wid >> 3, h = wid & 7;
  float x  = xp[n * HH + h * CD + lane];
  float vs = x * att_src[h * CD + lane];
  float vd = x * att_dst[h * CD + lane];
  #pragma unroll
  for (int off = 32; off; off >>= 1){
    vs += __shfl_xor(vs, off, 64);
    vd += __shfl_xor(vd, off, 64);
  }
  if (lane == 0){ a_s[wid] = vs; a_d[wid] = vd; }
}

// ---------------- CSR build (graph identical for both layers) ----------------
__global__ void init_deg_kernel(int* __restrict__ deg){
  int i = blockIdx.x * blockDim.x + threadIdx.x;
  if (i < NNODE) deg[i] = 1;                     // self loop
}

__global__ void count_deg_kernel(const int* __restrict__ ei, int* __restrict__ deg, int E){
  int t = blockIdx.x * blockDim.x + threadIdx.x;
  if (t < E) atomicAdd(&deg[ei[E + t]], 1);
}

__global__ __launch_bounds__(1024) void scan_kernel(const int* __restrict__ deg,
                                                    int* __restrict__ row_ptr,
                                                    int* __restrict__ cur){
  __shared__ int sums[1024];
  int t = threadIdx.x;
  const int PER = (NNODE + 1023) / 1024;         // 30
  int base = t * PER;
  int s = 0;
  for (int i = 0; i < PER; ++i){ int idx = base + i; if (idx < NNODE) s += deg[idx]; }
  sums[t] = s;
  __syncthreads();
  for (int off = 1; off < 1024; off <<= 1){
    int v = (t >= off) ? sums[t - off] : 0;
    __syncthreads();
    sums[t] += v;
    __syncthreads();
  }
  int run = (t == 0) ? 0 : sums[t - 1];
  for (int i = 0; i < PER; ++i){
    int idx = base + i;
    if (idx < NNODE){ row_ptr[idx] = run; cur[idx] = run; run += deg[idx]; }
  }
  if (t == 1023) row_ptr[NNODE] = sums[1023];
}

__global__ void scatter_kernel(const int* __restrict__ ei, int* __restrict__ cur,
                               int* __restrict__ col, int E){
  int t = blockIdx.x * blockDim.x + threadIdx.x;
  int total = E + NNODE;
  if (t >= total) return;
  int src, dst;
  if (t < E){ src = ei[t]; dst = ei[E + t]; }
  else      { src = t - E; dst = t - E; }
  int pos = atomicAdd(&cur[dst], 1);
  col[pos] = src;
}

// ---------------- fused per-(dst,head) softmax + aggregate (gather, no scatter atomics) ----------------
template <bool CONCAT>
__global__ __launch_bounds__(256) void gat_aggregate_kernel(
    const int* __restrict__ row_ptr, const int* __restrict__ col,
    const float* __restrict__ a_s, const float* __restrict__ a_d,
    const float* __restrict__ xp, float* __restrict__ out){
  int wid  = (blockIdx.x * blockDim.x + threadIdx.x) >> 6;   // (dst, head)
  int lane = threadIdx.x & 63;
  int wslot = threadIdx.x >> 6;                              // 0..3
  if (wid >= NNODE * HEADS) return;
  int n = wid >> 3, h = wid & 7;
  __shared__ float pbuf[4][CHUNK];
  __shared__ int   sbuf[4][CHUNK];
  int start = row_ptr[n], end = row_ptr[n + 1];
  float adnh = a_d[n * 8 + h];
  // phase 1: per-edge score + segment max
  float m = -INFINITY;
  for (int j0 = start; j0 < end; j0 += 64){
    int j = j0 + lane;
    if (j < end){
      int src = col[j];
      float e = a_s[src * 8 + h] + adnh;
      e = (e >= 0.f) ? e : SLOPE * e;
      int o = j - start;
      if (o < CHUNK){ sbuf[wslot][o] = src; pbuf[wslot][o] = e; }
      m = fmaxf(m, e);
    }
  }
  #pragma unroll
  for (int off = 32; off; off >>= 1) m = fmaxf(m, __shfl_xor(m, off, 64));
  // phase 2: exp + segment sum
  float s = 0.f;
  for (int j0 = start; j0 < end; j0 += 64){
    int j = j0 + lane;
    if (j < end){
      int o = j - start;
      float e;
      if (o < CHUNK) e = pbuf[wslot][o];
      else {
        int src = col[j];
        e = a_s[src * 8 + h] + adnh;
        e = (e >= 0.f) ? e : SLOPE * e;
      }
      float p = expf(e - m);
      if (o < CHUNK) pbuf[wslot][o] = p;
      s += p;
    }
  }
  #pragma unroll
  for (int off = 32; off; off >>= 1) s += __shfl_xor(s, off, 64);
  float inv = 1.0f / (s + 1e-16f);
  // phase 3: weighted gather of xp rows (lane = channel)
  float acc = 0.f;
  for (int j = start; j < end; ++j){
    int o = j - start;
    float p; int src;
    if (o < CHUNK){ p = pbuf[wslot][o]; src = sbuf[wslot][o]; }
    else {
      src = col[j];
      float e = a_s[src * 8 + h] + adnh;
      e = (e >= 0.f) ? e : SLOPE * e;
      p = expf(e - m);
    }
    acc += (p * inv) * xp[(size_t)src * HH + h * CD + lane];
  }
  if (CONCAT) out[(size_t)n * HH + h * CD + lane] = acc;
  else        atomicAdd(&out[n * CD + lane], 0.125f * acc);
}

__global__ void bias_add_kernel(float* __restrict__ out, const float* __restrict__ b,
                                int size, int width){
  int i = blockIdx.x * blockDim.x + threadIdx.x;
  if (i < size) out[i] += b[i % width];
}

// ---------------- host launch ----------------
extern "C" void kernel_launch(void* const* d_in, const int* in_sizes, int n_in,
                              void* d_out, int out_size, void* d_ws, size_t ws_size,
                              hipStream_t stream){
  const float* x   = (const float*)d_in[0];
  const int*   ei  = (const int*)  d_in[1];   // int32 (JAX x64 disabled)
  const float* W1  = (const float*)d_in[2];
  const float* as1 = (const float*)d_in[3];
  const float* ad1 = (const float*)d_in[4];
  const float* b1  = (const float*)d_in[5];
  const float* W2  = (const float*)d_in[6];
  const float* as2 = (const float*)d_in[7];
  const float* ad2 = (const float*)d_in[8];
  const float* b2  = (const float*)d_in[9];
  float* out = (float*)d_out;
  const int E = in_sizes[1] / 2;
  const int EN = E + NNODE;

  // workspace carve-up
  char* w = (char*)d_ws;
  float* hbuf = (float*)w; w += (size_t)NNODE * HH * 4;   // 61.44 MB
  float* xp   = (float*)w; w += (size_t)NNODE * HH * 4;   // 61.44 MB
  float* o1   = (float*)w; w += (size_t)NNODE * HH * 4;   // 61.44 MB
  float* a_s  = (float*)w; w += (size_t)NNODE * HEADS * 4;
  float* a_d  = (float*)w; w += (size_t)NNODE * HEADS * 4;
  int* deg     = (int*)w; w += (size_t)NNODE * 4;
  int* row_ptr = (int*)w; w += (size_t)(NNODE + 1) * 4;
  int* cur     = (int*)w; w += (size_t)NNODE * 4;
  int* col     = (int*)w; w += (size_t)EN * 4;

  // partitionable split of key(42)=(0,42): child j = tf(key,(0,j))
  unsigned k1a, k1b, k2a, k2b;
  tf2x32(0u, 42u, 0u, 0u, k1a, k1b);
  tf2x32(0u, 42u, 0u, 1u, k2a, k2b);

  const int total = NNODE * HH;                    // 15,360,000
  const int gemm_grid = ((NNODE + BM - 1) / BM) * (512 / BN);
  const int agg_grid = (NNODE * HEADS + 3) / 4;    // 4 waves/block

  // ---- CSR build (once; same graph both layers) ----
  init_deg_kernel<<<(NNODE + 255) / 256, 256, 0, stream>>>(deg);
  count_deg_kernel<<<(E + 255) / 256, 256, 0, stream>>>(ei, deg, E);
  scan_kernel<<<1, 1024, 0, stream>>>(deg, row_ptr, cur);
  scatter_kernel<<<(EN + 255) / 256, 256, 0, stream>>>(ei, cur, col, E);

  // ---- layer 1 ----
  dropelu_kernel<<<(total + 255) / 256, 256, 0, stream>>>(x, nullptr, hbuf, k1a, k1b, total, HH);
  gemm_f32_kernel<<<gemm_grid, 256, 0, stream>>>(hbuf, W1, xp, NNODE);
  attn_coef_kernel<<<(NNODE * HEADS + 3) / 4, 256, 0, stream>>>(xp, as1, ad1, a_s, a_d);
  gat_aggregate_kernel<true><<<agg_grid, 256, 0, stream>>>(row_ptr, col, a_s, a_d, xp, o1);

  // ---- layer 2 ----
  dropelu_kernel<<<(total + 255) / 256, 256, 0, stream>>>(o1, b1, hbuf, k2a, k2b, total, HH);
  gemm_f32_kernel<<<gemm_grid, 256, 0, stream>>>(hbuf, W2, xp, NNODE);
  attn_coef_kernel<<<(NNODE * HEADS + 3) / 4, 256, 0, stream>>>(xp, as2, ad2, a_s, a_d);
  hipMemsetAsync(out, 0, (size_t)NNODE * CD * 4, stream);
  gat_aggregate_kernel<false><<<agg_grid, 256, 0, stream>>>(row_ptr, col, a_s, a_d, xp, out);
  bias_add_kernel<<<(NNODE * CD + 255) / 256, 256, 0, stream>>>(out, b2, NNODE * CD, CD);
}

// Round 7
// 1022.980 us; speedup vs baseline: 2.8204x; 1.4522x over previous
//
#include <hip/hip_runtime.h>
#include <math.h>

#define HD __host__ __device__

static constexpr int NNODE = 30000;   // nodes
static constexpr int HH    = 512;     // HEADS*HID = hidden width (both layers)
static constexpr int HEADS = 8;
static constexpr int CD    = 64;      // channels per head
static constexpr float SLOPE = 0.2f;
static constexpr int CHUNK = 128;     // per-wave LDS cache in aggregate

typedef unsigned short bf16_t;
typedef __attribute__((ext_vector_type(8))) short short8;
typedef __attribute__((ext_vector_type(4))) float f32x4;
struct alignas(8) US4 { unsigned short x, y, z, w; };

__device__ inline float bf2f(unsigned short h){ return __uint_as_float((unsigned)h << 16); }
__device__ inline unsigned short f2bf_rne(float f){
  unsigned u = __float_as_uint(f);
  unsigned r = (u + 0x7FFFu + ((u >> 16) & 1u)) >> 16;
  return (unsigned short)r;
}

// ---------------- threefry2x32 (exact JAX semantics) ----------------
HD inline unsigned rotl32(unsigned v, int s){ return (v<<s) | (v>>(32-s)); }

HD inline void tf2x32(unsigned k0, unsigned k1, unsigned c0, unsigned c1,
                      unsigned &o0, unsigned &o1){
  unsigned ks2 = k0 ^ k1 ^ 0x1BD11BDAu;
  unsigned x0 = c0 + k0, x1 = c1 + k1;
  x0+=x1; x1=rotl32(x1,13); x1^=x0;
  x0+=x1; x1=rotl32(x1,15); x1^=x0;
  x0+=x1; x1=rotl32(x1,26); x1^=x0;
  x0+=x1; x1=rotl32(x1, 6); x1^=x0;
  x0 += k1; x1 += ks2 + 1u;
  x0+=x1; x1=rotl32(x1,17); x1^=x0;
  x0+=x1; x1=rotl32(x1,29); x1^=x0;
  x0+=x1; x1=rotl32(x1,16); x1^=x0;
  x0+=x1; x1=rotl32(x1,24); x1^=x0;
  x0 += ks2; x1 += k0 + 2u;
  x0+=x1; x1=rotl32(x1,13); x1^=x0;
  x0+=x1; x1=rotl32(x1,15); x1^=x0;
  x0+=x1; x1=rotl32(x1,26); x1^=x0;
  x0+=x1; x1=rotl32(x1, 6); x1^=x0;
  x0 += k0; x1 += k1 + 3u;
  x0+=x1; x1=rotl32(x1,17); x1^=x0;
  x0+=x1; x1=rotl32(x1,29); x1^=x0;
  x0+=x1; x1=rotl32(x1,16); x1^=x0;
  x0+=x1; x1=rotl32(x1,24); x1^=x0;
  x0 += k1; x1 += ks2 + 4u;
  x0+=x1; x1=rotl32(x1,13); x1^=x0;
  x0+=x1; x1=rotl32(x1,15); x1^=x0;
  x0+=x1; x1=rotl32(x1,26); x1^=x0;
  x0+=x1; x1=rotl32(x1, 6); x1^=x0;
  x0 += ks2; x1 += k0 + 5u;
  o0 = x0; o1 = x1;
}

// ---------------- dropout + (bias) + ELU -> bf16 hi/lo split, x4 per thread ----------------
// jax_threefry_partitionable: bits[e] = o0^o1, (o0,o1)=tf(key,(0,e))
__global__ void dropelu_split_kernel(const float* __restrict__ in, const float* __restrict__ bias,
                                     bf16_t* __restrict__ hi, bf16_t* __restrict__ lo,
                                     unsigned key0, unsigned key1, int total4, int width){
  int i = blockIdx.x * blockDim.x + threadIdx.x;
  if (i >= total4) return;
  int e0 = i * 4;
  float4 v4 = *reinterpret_cast<const float4*>(&in[e0]);
  float vv[4] = {v4.x, v4.y, v4.z, v4.w};
  if (bias){
    float4 b4 = *reinterpret_cast<const float4*>(&bias[e0 % width]);
    vv[0]+=b4.x; vv[1]+=b4.y; vv[2]+=b4.z; vv[3]+=b4.w;
  }
  US4 h4, l4;
  unsigned short* hp = &h4.x; unsigned short* lp = &l4.x;
  #pragma unroll
  for (int j = 0; j < 4; ++j){
    unsigned o0, o1;
    tf2x32(key0, key1, 0u, (unsigned)(e0 + j), o0, o1);
    unsigned bits = o0 ^ o1;
    float u = __uint_as_float((bits >> 9) | 0x3f800000u) - 1.0f;  // [0,1)
    float v = vv[j];
    v = (u < 0.8f) ? (v * 1.25f) : 0.0f;         // dropout keep-prob 0.8
    v = (v > 0.0f) ? v : expm1f(v);              // ELU
    unsigned short hh = f2bf_rne(v);
    hp[j] = hh;
    lp[j] = f2bf_rne(v - bf2f(hh));
  }
  *reinterpret_cast<US4*>(&hi[e0]) = h4;
  *reinterpret_cast<US4*>(&lo[e0]) = l4;
}

// ---------------- W[512x512] -> transposed bf16 hi/lo split ----------------
__global__ void splitW_kernel(const float* __restrict__ W, bf16_t* __restrict__ Wthi,
                              bf16_t* __restrict__ Wtlo){
  int idx = blockIdx.x * blockDim.x + threadIdx.x;   // = j*512 + k  (output index)
  if (idx >= 512 * 512) return;
  int j = idx >> 9, k = idx & 511;
  float v = W[k * 512 + j];                          // strided read, W is L2-resident (1 MB)
  unsigned short hh = f2bf_rne(v);
  Wthi[idx] = hh;
  Wtlo[idx] = f2bf_rne(v - bf2f(hh));
}

// ---------------- MFMA GEMM: C[M,512] = (Ahi+Alo) @ (Bhi+Blo), bf16x3 ----------------
// A: [M][512] bf16 hi/lo.  Bt: [512 cols][512 k] transposed bf16 hi/lo.
#define LSTR 40   // LDS row stride (elements): 80B rows -> <=2-way bank aliasing
__global__ __launch_bounds__(256) void gemm_mfma_kernel(
    const bf16_t* __restrict__ Ahi, const bf16_t* __restrict__ Alo,
    const bf16_t* __restrict__ Bthi, const bf16_t* __restrict__ Btlo,
    float* __restrict__ C, int M){
  __shared__ bf16_t lAhi[128][LSTR], lAlo[128][LSTR], lBhi[128][LSTR], lBlo[128][LSTR];
  int t  = threadIdx.x;
  int bx = blockIdx.x & 3;          // col block (512/128)
  int by = blockIdx.x >> 2;
  int row0 = by * 128, col0 = bx * 128;
  int lane = t & 63, wid = t >> 6;
  int wr = wid >> 1, wc = wid & 1;  // wave 64x64 sub-tile
  f32x4 acc[4][4] = {};
  int srow  = t >> 1;               // staging row/col 0..127
  int skoff = (t & 1) * 16;         // 0 or 16
  int frow = lane & 15, fk = (lane >> 4) * 8;
  for (int k0 = 0; k0 < 512; k0 += 32){
    // stage A (128 rows x 32 k, hi+lo) — rows >= M read in-bounds-of-ws garbage, never stored
    {
      const bf16_t* pa = &Ahi[(size_t)(row0 + srow) * 512 + k0 + skoff];
      *reinterpret_cast<short8*>(&lAhi[srow][skoff])     = *reinterpret_cast<const short8*>(pa);
      *reinterpret_cast<short8*>(&lAhi[srow][skoff + 8]) = *reinterpret_cast<const short8*>(pa + 8);
      const bf16_t* pl = &Alo[(size_t)(row0 + srow) * 512 + k0 + skoff];
      *reinterpret_cast<short8*>(&lAlo[srow][skoff])     = *reinterpret_cast<const short8*>(pl);
      *reinterpret_cast<short8*>(&lAlo[srow][skoff + 8]) = *reinterpret_cast<const short8*>(pl + 8);
      const bf16_t* pb = &Bthi[(size_t)(col0 + srow) * 512 + k0 + skoff];
      *reinterpret_cast<short8*>(&lBhi[srow][skoff])     = *reinterpret_cast<const short8*>(pb);
      *reinterpret_cast<short8*>(&lBhi[srow][skoff + 8]) = *reinterpret_cast<const short8*>(pb + 8);
      const bf16_t* pc = &Btlo[(size_t)(col0 + srow) * 512 + k0 + skoff];
      *reinterpret_cast<short8*>(&lBlo[srow][skoff])     = *reinterpret_cast<const short8*>(pc);
      *reinterpret_cast<short8*>(&lBlo[srow][skoff + 8]) = *reinterpret_cast<const short8*>(pc + 8);
    }
    __syncthreads();
    short8 fahi[4], falo[4], fbhi[4], fblo[4];
    #pragma unroll
    for (int m = 0; m < 4; ++m){
      fahi[m] = *reinterpret_cast<const short8*>(&lAhi[wr*64 + m*16 + frow][fk]);
      falo[m] = *reinterpret_cast<const short8*>(&lAlo[wr*64 + m*16 + frow][fk]);
    }
    #pragma unroll
    for (int n = 0; n < 4; ++n){
      fbhi[n] = *reinterpret_cast<const short8*>(&lBhi[wc*64 + n*16 + frow][fk]);
      fblo[n] = *reinterpret_cast<const short8*>(&lBlo[wc*64 + n*16 + frow][fk]);
    }
    #pragma unroll
    for (int m = 0; m < 4; ++m)
      #pragma unroll
      for (int n = 0; n < 4; ++n){
        acc[m][n] = __builtin_amdgcn_mfma_f32_16x16x32_bf16(fahi[m], fbhi[n], acc[m][n], 0, 0, 0);
        acc[m][n] = __builtin_amdgcn_mfma_f32_16x16x32_bf16(fahi[m], fblo[n], acc[m][n], 0, 0, 0);
        acc[m][n] = __builtin_amdgcn_mfma_f32_16x16x32_bf16(falo[m], fbhi[n], acc[m][n], 0, 0, 0);
      }
    __syncthreads();
  }
  // write C: D layout row=(lane>>4)*4+r, col=lane&15
  int rbase = row0 + wr * 64 + (lane >> 4) * 4;
  int cbase = col0 + wc * 64 + (lane & 15);
  #pragma unroll
  for (int m = 0; m < 4; ++m)
    #pragma unroll
    for (int n = 0; n < 4; ++n)
      #pragma unroll
      for (int r = 0; r < 4; ++r){
        int gr = rbase + m * 16 + r;
        if (gr < M) C[(size_t)gr * 512 + cbase + n * 16] = acc[m][n][r];
      }
}

// ---------------- attention coefficients: a_s/a_d [N, HEADS] ----------------
__global__ void attn_coef_kernel(const float* __restrict__ xp, const float* __restrict__ att_src,
                                 const float* __restrict__ att_dst,
                                 float* __restrict__ a_s, float* __restrict__ a_d){
  int wid = (blockIdx.x * blockDim.x + threadIdx.x) >> 6;
  int lane = threadIdx.x & 63;
  if (wid >= NNODE * HEADS) return;
  int n = wid >> 3, h = wid & 7;
  float x  = xp[n * HH + h * CD + lane];
  float vs = x * att_src[h * CD + lane];
  float vd = x * att_dst[h * CD + lane];
  #pragma unroll
  for (int off = 32; off; off >>= 1){
    vs += __shfl_xor(vs, off, 64);
    vd += __shfl_xor(vd, off, 64);
  }
  if (lane == 0){ a_s[wid] = vs; a_d[wid] = vd; }
}

// ---------------- CSR build (graph identical for both layers) ----------------
__global__ void init_deg_kernel(int* __restrict__ deg){
  int i = blockIdx.x * blockDim.x + threadIdx.x;
  if (i < NNODE) deg[i] = 1;                     // self loop
}

__global__ void count_deg_kernel(const int* __restrict__ ei, int* __restrict__ deg, int E){
  int t = blockIdx.x * blockDim.x + threadIdx.x;
  if (t < E) atomicAdd(&deg[ei[E + t]], 1);
}

__global__ __launch_bounds__(1024) void scan_kernel(const int* __restrict__ deg,
                                                    int* __restrict__ row_ptr,
                                                    int* __restrict__ cur){
  __shared__ int sums[1024];
  int t = threadIdx.x;
  const int PER = (NNODE + 1023) / 1024;
  int base = t * PER;
  int s = 0;
  for (int i = 0; i < PER; ++i){ int idx = base + i; if (idx < NNODE) s += deg[idx]; }
  sums[t] = s;
  __syncthreads();
  for (int off = 1; off < 1024; off <<= 1){
    int v = (t >= off) ? sums[t - off] : 0;
    __syncthreads();
    sums[t] += v;
    __syncthreads();
  }
  int run = (t == 0) ? 0 : sums[t - 1];
  for (int i = 0; i < PER; ++i){
    int idx = base + i;
    if (idx < NNODE){ row_ptr[idx] = run; cur[idx] = run; run += deg[idx]; }
  }
  if (t == 1023) row_ptr[NNODE] = sums[1023];
}

__global__ void scatter_kernel(const int* __restrict__ ei, int* __restrict__ cur,
                               int* __restrict__ col, int E){
  int t = blockIdx.x * blockDim.x + threadIdx.x;
  int total = E + NNODE;
  if (t >= total) return;
  int src, dst;
  if (t < E){ src = ei[t]; dst = ei[E + t]; }
  else      { src = t - E; dst = t - E; }
  int pos = atomicAdd(&cur[dst], 1);
  col[pos] = src;
}

// ---------------- fused per-(dst,head) softmax + aggregate (gather) ----------------
template <bool CONCAT>
__global__ __launch_bounds__(256) void gat_aggregate_kernel(
    const int* __restrict__ row_ptr, const int* __restrict__ col,
    const float* __restrict__ a_s, const float* __restrict__ a_d,
    const float* __restrict__ xp, float* __restrict__ out){
  int wid  = (blockIdx.x * blockDim.x + threadIdx.x) >> 6;   // (dst, head)
  int lane = threadIdx.x & 63;
  int wslot = threadIdx.x >> 6;
  if (wid >= NNODE * HEADS) return;
  int n = wid >> 3, h = wid & 7;
  __shared__ float pbuf[4][CHUNK];
  __shared__ int   sbuf[4][CHUNK];
  int start = row_ptr[n], end = row_ptr[n + 1];
  float adnh = a_d[n * 8 + h];
  float m = -INFINITY;
  for (int j0 = start; j0 < end; j0 += 64){
    int j = j0 + lane;
    if (j < end){
      int src = col[j];
      float e = a_s[src * 8 + h] + adnh;
      e = (e >= 0.f) ? e : SLOPE * e;
      int o = j - start;
      if (o < CHUNK){ sbuf[wslot][o] = src; pbuf[wslot][o] = e; }
      m = fmaxf(m, e);
    }
  }
  #pragma unroll
  for (int off = 32; off; off >>= 1) m = fmaxf(m, __shfl_xor(m, off, 64));
  float s = 0.f;
  for (int j0 = start; j0 < end; j0 += 64){
    int j = j0 + lane;
    if (j < end){
      int o = j - start;
      float e;
      if (o < CHUNK) e = pbuf[wslot][o];
      else {
        int src = col[j];
        e = a_s[src * 8 + h] + adnh;
        e = (e >= 0.f) ? e : SLOPE * e;
      }
      float p = expf(e - m);
      if (o < CHUNK) pbuf[wslot][o] = p;
      s += p;
    }
  }
  #pragma unroll
  for (int off = 32; off; off >>= 1) s += __shfl_xor(s, off, 64);
  float inv = 1.0f / (s + 1e-16f);
  float acc = 0.f;
  for (int j = start; j < end; ++j){
    int o = j - start;
    float p; int src;
    if (o < CHUNK){ p = pbuf[wslot][o]; src = sbuf[wslot][o]; }
    else {
      src = col[j];
      float e = a_s[src * 8 + h] + adnh;
      e = (e >= 0.f) ? e : SLOPE * e;
      p = expf(e - m);
    }
    acc += (p * inv) * xp[(size_t)src * HH + h * CD + lane];
  }
  if (CONCAT) out[(size_t)n * HH + h * CD + lane] = acc;
  else        atomicAdd(&out[n * CD + lane], 0.125f * acc);
}

__global__ void bias_add_kernel(float* __restrict__ out, const float* __restrict__ b,
                                int size, int width){
  int i = blockIdx.x * blockDim.x + threadIdx.x;
  if (i < size) out[i] += b[i % width];
}

// ---------------- host launch ----------------
extern "C" void kernel_launch(void* const* d_in, const int* in_sizes, int n_in,
                              void* d_out, int out_size, void* d_ws, size_t ws_size,
                              hipStream_t stream){
  const float* x   = (const float*)d_in[0];
  const int*   ei  = (const int*)  d_in[1];
  const float* W1  = (const float*)d_in[2];
  const float* as1 = (const float*)d_in[3];
  const float* ad1 = (const float*)d_in[4];
  const float* b1  = (const float*)d_in[5];
  const float* W2  = (const float*)d_in[6];
  const float* as2 = (const float*)d_in[7];
  const float* ad2 = (const float*)d_in[8];
  const float* b2  = (const float*)d_in[9];
  float* out = (float*)d_out;
  const int E = in_sizes[1] / 2;
  const int EN = E + NNODE;

  // workspace carve-up (~191 MB)
  char* w = (char*)d_ws;
  bf16_t* Ahi = (bf16_t*)w; w += (size_t)NNODE * HH * 2;     // 30.72 MB
  bf16_t* Alo = (bf16_t*)w; w += (size_t)NNODE * HH * 2;     // 30.72 MB
  float* xp   = (float*)w;  w += (size_t)NNODE * HH * 4;     // 61.44 MB
  float* o1   = (float*)w;  w += (size_t)NNODE * HH * 4;     // 61.44 MB
  bf16_t* Wt1hi = (bf16_t*)w; w += (size_t)512 * 512 * 2;
  bf16_t* Wt1lo = (bf16_t*)w; w += (size_t)512 * 512 * 2;
  bf16_t* Wt2hi = (bf16_t*)w; w += (size_t)512 * 512 * 2;
  bf16_t* Wt2lo = (bf16_t*)w; w += (size_t)512 * 512 * 2;
  float* a_s  = (float*)w; w += (size_t)NNODE * HEADS * 4;
  float* a_d  = (float*)w; w += (size_t)NNODE * HEADS * 4;
  int* deg     = (int*)w; w += (size_t)NNODE * 4;
  int* row_ptr = (int*)w; w += (size_t)(NNODE + 1) * 4;
  int* cur     = (int*)w; w += (size_t)NNODE * 4;
  int* col     = (int*)w; w += (size_t)EN * 4;

  // partitionable split of key(42)=(0,42): child j = tf(key,(0,j))
  unsigned k1a, k1b, k2a, k2b;
  tf2x32(0u, 42u, 0u, 0u, k1a, k1b);
  tf2x32(0u, 42u, 0u, 1u, k2a, k2b);

  const int total4 = NNODE * HH / 4;               // 3,840,000
  const int gemm_grid = ((NNODE + 127) / 128) * 4; // 940
  const int agg_grid = (NNODE * HEADS + 3) / 4;

  // ---- one-time prep ----
  splitW_kernel<<<1024, 256, 0, stream>>>(W1, Wt1hi, Wt1lo);
  splitW_kernel<<<1024, 256, 0, stream>>>(W2, Wt2hi, Wt2lo);
  init_deg_kernel<<<(NNODE + 255) / 256, 256, 0, stream>>>(deg);
  count_deg_kernel<<<(E + 255) / 256, 256, 0, stream>>>(ei, deg, E);
  scan_kernel<<<1, 1024, 0, stream>>>(deg, row_ptr, cur);
  scatter_kernel<<<(EN + 255) / 256, 256, 0, stream>>>(ei, cur, col, E);

  // ---- layer 1 ----
  dropelu_split_kernel<<<(total4 + 255) / 256, 256, 0, stream>>>(x, nullptr, Ahi, Alo, k1a, k1b, total4, HH);
  gemm_mfma_kernel<<<gemm_grid, 256, 0, stream>>>(Ahi, Alo, Wt1hi, Wt1lo, xp, NNODE);
  attn_coef_kernel<<<(NNODE * HEADS + 3) / 4, 256, 0, stream>>>(xp, as1, ad1, a_s, a_d);
  gat_aggregate_kernel<true><<<agg_grid, 256, 0, stream>>>(row_ptr, col, a_s, a_d, xp, o1);

  // ---- layer 2 ----
  dropelu_split_kernel<<<(total4 + 255) / 256, 256, 0, stream>>>(o1, b1, Ahi, Alo, k2a, k2b, total4, HH);
  gemm_mfma_kernel<<<gemm_grid, 256, 0, stream>>>(Ahi, Alo, Wt2hi, Wt2lo, xp, NNODE);
  attn_coef_kernel<<<(NNODE * HEADS + 3) / 4, 256, 0, stream>>>(xp, as2, ad2, a_s, a_d);
  hipMemsetAsync(out, 0, (size_t)NNODE * CD * 4, stream);
  gat_aggregate_kernel<false><<<agg_grid, 256, 0, stream>>>(row_ptr, col, a_s, a_d, xp, out);
  bias_add_kernel<<<(NNODE * CD + 255) / 256, 256, 0, stream>>>(out, b2, NNODE * CD, CD);
}

// Round 8
// 767.738 us; speedup vs baseline: 3.7581x; 1.3325x over previous
//
#include <hip/hip_runtime.h>
#include <math.h>

#define HD __host__ __device__

static constexpr int NNODE = 30000;   // nodes
static constexpr int HH    = 512;     // HEADS*HID = hidden width (both layers)
static constexpr int HEADS = 8;
static constexpr int CD    = 64;      // channels per head
static constexpr float SLOPE = 0.2f;
static constexpr int TILE = 128;      // edges per aggregation tile

typedef unsigned short bf16_t;
typedef __attribute__((ext_vector_type(8))) short short8;
typedef __attribute__((ext_vector_type(4))) float f32x4;
struct alignas(8) US4 { unsigned short x, y, z, w; };

__device__ inline float bf2f(unsigned short h){ return __uint_as_float((unsigned)h << 16); }
__device__ inline unsigned short f2bf_rne(float f){
  unsigned u = __float_as_uint(f);
  unsigned r = (u + 0x7FFFu + ((u >> 16) & 1u)) >> 16;
  return (unsigned short)r;
}

// ---------------- threefry2x32 (exact JAX semantics) ----------------
HD inline unsigned rotl32(unsigned v, int s){ return (v<<s) | (v>>(32-s)); }

HD inline void tf2x32(unsigned k0, unsigned k1, unsigned c0, unsigned c1,
                      unsigned &o0, unsigned &o1){
  unsigned ks2 = k0 ^ k1 ^ 0x1BD11BDAu;
  unsigned x0 = c0 + k0, x1 = c1 + k1;
  x0+=x1; x1=rotl32(x1,13); x1^=x0;
  x0+=x1; x1=rotl32(x1,15); x1^=x0;
  x0+=x1; x1=rotl32(x1,26); x1^=x0;
  x0+=x1; x1=rotl32(x1, 6); x1^=x0;
  x0 += k1; x1 += ks2 + 1u;
  x0+=x1; x1=rotl32(x1,17); x1^=x0;
  x0+=x1; x1=rotl32(x1,29); x1^=x0;
  x0+=x1; x1=rotl32(x1,16); x1^=x0;
  x0+=x1; x1=rotl32(x1,24); x1^=x0;
  x0 += ks2; x1 += k0 + 2u;
  x0+=x1; x1=rotl32(x1,13); x1^=x0;
  x0+=x1; x1=rotl32(x1,15); x1^=x0;
  x0+=x1; x1=rotl32(x1,26); x1^=x0;
  x0+=x1; x1=rotl32(x1, 6); x1^=x0;
  x0 += k0; x1 += k1 + 3u;
  x0+=x1; x1=rotl32(x1,17); x1^=x0;
  x0+=x1; x1=rotl32(x1,29); x1^=x0;
  x0+=x1; x1=rotl32(x1,16); x1^=x0;
  x0+=x1; x1=rotl32(x1,24); x1^=x0;
  x0 += k1; x1 += ks2 + 4u;
  x0+=x1; x1=rotl32(x1,13); x1^=x0;
  x0+=x1; x1=rotl32(x1,15); x1^=x0;
  x0+=x1; x1=rotl32(x1,26); x1^=x0;
  x0+=x1; x1=rotl32(x1, 6); x1^=x0;
  x0 += ks2; x1 += k0 + 5u;
  o0 = x0; o1 = x1;
}

// ---------------- dropout + (bias) + ELU -> bf16 hi/lo split, x4 per thread ----------------
__global__ void dropelu_split_kernel(const float* __restrict__ in, const float* __restrict__ bias,
                                     bf16_t* __restrict__ hi, bf16_t* __restrict__ lo,
                                     unsigned key0, unsigned key1, int total4, int width){
  int i = blockIdx.x * blockDim.x + threadIdx.x;
  if (i >= total4) return;
  int e0 = i * 4;
  float4 v4 = *reinterpret_cast<const float4*>(&in[e0]);
  float vv[4] = {v4.x, v4.y, v4.z, v4.w};
  if (bias){
    float4 b4 = *reinterpret_cast<const float4*>(&bias[e0 % width]);
    vv[0]+=b4.x; vv[1]+=b4.y; vv[2]+=b4.z; vv[3]+=b4.w;
  }
  US4 h4, l4;
  unsigned short* hp = &h4.x; unsigned short* lp = &l4.x;
  #pragma unroll
  for (int j = 0; j < 4; ++j){
    unsigned o0, o1;
    tf2x32(key0, key1, 0u, (unsigned)(e0 + j), o0, o1);
    unsigned bits = o0 ^ o1;
    float u = __uint_as_float((bits >> 9) | 0x3f800000u) - 1.0f;  // [0,1)
    float v = vv[j];
    v = (u < 0.8f) ? (v * 1.25f) : 0.0f;         // dropout keep-prob 0.8
    v = (v > 0.0f) ? v : expm1f(v);              // ELU
    unsigned short hh = f2bf_rne(v);
    hp[j] = hh;
    lp[j] = f2bf_rne(v - bf2f(hh));
  }
  *reinterpret_cast<US4*>(&hi[e0]) = h4;
  *reinterpret_cast<US4*>(&lo[e0]) = l4;
}

// ---------------- W[512x512] -> transposed bf16 hi/lo split ----------------
__global__ void splitW_kernel(const float* __restrict__ W, bf16_t* __restrict__ Wthi,
                              bf16_t* __restrict__ Wtlo){
  int idx = blockIdx.x * blockDim.x + threadIdx.x;
  if (idx >= 512 * 512) return;
  int j = idx >> 9, k = idx & 511;
  float v = W[k * 512 + j];
  unsigned short hh = f2bf_rne(v);
  Wthi[idx] = hh;
  Wtlo[idx] = f2bf_rne(v - bf2f(hh));
}

// ---------------- MFMA GEMM: C[M,512] = (Ahi+Alo) @ (Bhi+Blo), bf16x3 ----------------
#define LSTR 40
__global__ __launch_bounds__(256) void gemm_mfma_kernel(
    const bf16_t* __restrict__ Ahi, const bf16_t* __restrict__ Alo,
    const bf16_t* __restrict__ Bthi, const bf16_t* __restrict__ Btlo,
    float* __restrict__ C, int M){
  __shared__ bf16_t lAhi[128][LSTR], lAlo[128][LSTR], lBhi[128][LSTR], lBlo[128][LSTR];
  int t  = threadIdx.x;
  int bx = blockIdx.x & 3;
  int by = blockIdx.x >> 2;
  int row0 = by * 128, col0 = bx * 128;
  int lane = t & 63, wid = t >> 6;
  int wr = wid >> 1, wc = wid & 1;
  f32x4 acc[4][4] = {};
  int srow  = t >> 1;
  int skoff = (t & 1) * 16;
  int frow = lane & 15, fk = (lane >> 4) * 8;
  for (int k0 = 0; k0 < 512; k0 += 32){
    {
      const bf16_t* pa = &Ahi[(size_t)(row0 + srow) * 512 + k0 + skoff];
      *reinterpret_cast<short8*>(&lAhi[srow][skoff])     = *reinterpret_cast<const short8*>(pa);
      *reinterpret_cast<short8*>(&lAhi[srow][skoff + 8]) = *reinterpret_cast<const short8*>(pa + 8);
      const bf16_t* pl = &Alo[(size_t)(row0 + srow) * 512 + k0 + skoff];
      *reinterpret_cast<short8*>(&lAlo[srow][skoff])     = *reinterpret_cast<const short8*>(pl);
      *reinterpret_cast<short8*>(&lAlo[srow][skoff + 8]) = *reinterpret_cast<const short8*>(pl + 8);
      const bf16_t* pb = &Bthi[(size_t)(col0 + srow) * 512 + k0 + skoff];
      *reinterpret_cast<short8*>(&lBhi[srow][skoff])     = *reinterpret_cast<const short8*>(pb);
      *reinterpret_cast<short8*>(&lBhi[srow][skoff + 8]) = *reinterpret_cast<const short8*>(pb + 8);
      const bf16_t* pc = &Btlo[(size_t)(col0 + srow) * 512 + k0 + skoff];
      *reinterpret_cast<short8*>(&lBlo[srow][skoff])     = *reinterpret_cast<const short8*>(pc);
      *reinterpret_cast<short8*>(&lBlo[srow][skoff + 8]) = *reinterpret_cast<const short8*>(pc + 8);
    }
    __syncthreads();
    short8 fahi[4], falo[4], fbhi[4], fblo[4];
    #pragma unroll
    for (int m = 0; m < 4; ++m){
      fahi[m] = *reinterpret_cast<const short8*>(&lAhi[wr*64 + m*16 + frow][fk]);
      falo[m] = *reinterpret_cast<const short8*>(&lAlo[wr*64 + m*16 + frow][fk]);
    }
    #pragma unroll
    for (int n = 0; n < 4; ++n){
      fbhi[n] = *reinterpret_cast<const short8*>(&lBhi[wc*64 + n*16 + frow][fk]);
      fblo[n] = *reinterpret_cast<const short8*>(&lBlo[wc*64 + n*16 + frow][fk]);
    }
    #pragma unroll
    for (int m = 0; m < 4; ++m)
      #pragma unroll
      for (int n = 0; n < 4; ++n){
        acc[m][n] = __builtin_amdgcn_mfma_f32_16x16x32_bf16(fahi[m], fbhi[n], acc[m][n], 0, 0, 0);
        acc[m][n] = __builtin_amdgcn_mfma_f32_16x16x32_bf16(fahi[m], fblo[n], acc[m][n], 0, 0, 0);
        acc[m][n] = __builtin_amdgcn_mfma_f32_16x16x32_bf16(falo[m], fbhi[n], acc[m][n], 0, 0, 0);
      }
    __syncthreads();
  }
  int rbase = row0 + wr * 64 + (lane >> 4) * 4;
  int cbase = col0 + wc * 64 + (lane & 15);
  #pragma unroll
  for (int m = 0; m < 4; ++m)
    #pragma unroll
    for (int n = 0; n < 4; ++n)
      #pragma unroll
      for (int r = 0; r < 4; ++r){
        int gr = rbase + m * 16 + r;
        if (gr < M) C[(size_t)gr * 512 + cbase + n * 16] = acc[m][n][r];
      }
}

// ---------------- attention coefficients: a_s/a_d [N, HEADS] ----------------
__global__ void attn_coef_kernel(const float* __restrict__ xp, const float* __restrict__ att_src,
                                 const float* __restrict__ att_dst,
                                 float* __restrict__ a_s, float* __restrict__ a_d){
  int wid = (blockIdx.x * blockDim.x + threadIdx.x) >> 6;
  int lane = threadIdx.x & 63;
  if (wid >= NNODE * HEADS) return;
  int n = wid >> 3, h = wid & 7;
  float x  = xp[n * HH + h * CD + lane];
  float vs = x * att_src[h * CD + lane];
  float vd = x * att_dst[h * CD + lane];
  #pragma unroll
  for (int off = 32; off; off >>= 1){
    vs += __shfl_xor(vs, off, 64);
    vd += __shfl_xor(vd, off, 64);
  }
  if (lane == 0){ a_s[wid] = vs; a_d[wid] = vd; }
}

// ---------------- CSR build ----------------
__global__ void init_deg_kernel(int* __restrict__ deg){
  int i = blockIdx.x * blockDim.x + threadIdx.x;
  if (i < NNODE) deg[i] = 1;                     // self loop
}

__global__ void count_deg_kernel(const int* __restrict__ ei, int* __restrict__ deg, int E){
  int t = blockIdx.x * blockDim.x + threadIdx.x;
  if (t < E) atomicAdd(&deg[ei[E + t]], 1);
}

__global__ __launch_bounds__(1024) void scan_kernel(const int* __restrict__ deg,
                                                    int* __restrict__ row_ptr,
                                                    int* __restrict__ cur){
  __shared__ int sums[1024];
  int t = threadIdx.x;
  const int PER = (NNODE + 1023) / 1024;
  int base = t * PER;
  int s = 0;
  for (int i = 0; i < PER; ++i){ int idx = base + i; if (idx < NNODE) s += deg[idx]; }
  sums[t] = s;
  __syncthreads();
  for (int off = 1; off < 1024; off <<= 1){
    int v = (t >= off) ? sums[t - off] : 0;
    __syncthreads();
    sums[t] += v;
    __syncthreads();
  }
  int run = (t == 0) ? 0 : sums[t - 1];
  for (int i = 0; i < PER; ++i){
    int idx = base + i;
    if (idx < NNODE){ row_ptr[idx] = run; cur[idx] = run; run += deg[idx]; }
  }
  if (t == 1023) row_ptr[NNODE] = sums[1023];
}

__global__ void scatter_kernel(const int* __restrict__ ei, int* __restrict__ cur,
                               int* __restrict__ col, int E){
  int t = blockIdx.x * blockDim.x + threadIdx.x;
  int total = E + NNODE;
  if (t >= total) return;
  int src, dst;
  if (t < E){ src = ei[t]; dst = ei[E + t]; }
  else      { src = t - E; dst = t - E; }
  int pos = atomicAdd(&cur[dst], 1);
  col[pos] = src;
}

// ---------------- block-per-dst fused softmax + aggregate (all 8 heads) ----------------
// Online-softmax over edge tiles of TILE; thread tid owns channels 2*tid, 2*tid+1
// of the 512-wide gathered row (h2 = tid>>5). Score work-items use h = tid&7.
template <bool CONCAT>
__global__ __launch_bounds__(256) void gat_aggregate2_kernel(
    const int* __restrict__ row_ptr, const int* __restrict__ col,
    const float* __restrict__ a_s, const float* __restrict__ a_d,
    const float* __restrict__ xp, const float* __restrict__ bias,
    float* __restrict__ out){
  int n   = blockIdx.x;
  int tid = threadIdx.x;
  int lane = tid & 63, wslot = tid >> 6;
  int h  = tid & 7;          // score-phase head
  int h2 = tid >> 5;         // channel-phase head
  __shared__ int   scol[TILE];
  __shared__ float sp[TILE][8];     // scores -> p values
  __shared__ float red[32];         // 4 waves x 8 heads
  __shared__ float m_run[8], s_run[8], nm[8], fr[8];
  int start = row_ptr[n], end = row_ptr[n + 1];
  int deg = end - start;
  if (tid < 8){ m_run[tid] = -INFINITY; s_run[tid] = 0.f; }
  float adh = a_d[n * 8 + h];
  float acc0 = 0.f, acc1 = 0.f;
  for (int base = 0; base < deg; base += TILE){
    int len = min(TILE, deg - base);
    __syncthreads();                      // scol/sp free from previous tile
    if (tid < TILE) scol[tid] = (tid < len) ? col[start + base + tid] : 0;
    __syncthreads();
    // ---- scores + per-head tile max ----
    float mpart = -INFINITY;
    #pragma unroll
    for (int k = 0; k < TILE * 8 / 256; ++k){
      int j = (tid >> 3) + k * 32;
      float e = -INFINITY;
      if (j < len){
        int src = scol[j];
        e = a_s[src * 8 + h] + adh;
        e = (e >= 0.f) ? e : SLOPE * e;
      }
      sp[j][h] = e;
      mpart = fmaxf(mpart, e);
    }
    #pragma unroll
    for (int off = 8; off < 64; off <<= 1) mpart = fmaxf(mpart, __shfl_xor(mpart, off, 64));
    if (lane < 8) red[wslot * 8 + lane] = mpart;
    __syncthreads();
    if (tid < 8){
      float tm = fmaxf(fmaxf(red[tid], red[8 + tid]), fmaxf(red[16 + tid], red[24 + tid]));
      float om = m_run[tid];
      float nmv = fmaxf(om, tm);
      nm[tid] = nmv;
      fr[tid] = expf(om - nmv);           // 0 on first tile (om = -inf)
      m_run[tid] = nmv;
    }
    __syncthreads();
    // ---- p = exp(e - m) + per-head tile sum ----
    float nmh = nm[h];
    float spart = 0.f;
    #pragma unroll
    for (int k = 0; k < TILE * 8 / 256; ++k){
      int j = (tid >> 3) + k * 32;
      float p = expf(sp[j][h] - nmh);     // pad rows: exp(-inf) = 0
      sp[j][h] = p;
      spart += p;
    }
    #pragma unroll
    for (int off = 8; off < 64; off <<= 1) spart += __shfl_xor(spart, off, 64);
    __syncthreads();                      // red free (consumed above)
    if (lane < 8) red[wslot * 8 + lane] = spart;
    __syncthreads();
    if (tid < 8){
      float ts = red[tid] + red[8 + tid] + red[16 + tid] + red[24 + tid];
      s_run[tid] = s_run[tid] * fr[tid] + ts;
    }
    // ---- rescale acc, then accumulate this tile ----
    float facc = fr[h2];
    acc0 *= facc; acc1 *= facc;
    int c0 = 2 * tid;
    for (int j = 0; j < len; ++j){
      float p = sp[j][h2];
      int src = scol[j];
      float2 v = *reinterpret_cast<const float2*>(&xp[(size_t)src * 512 + c0]);
      acc0 += p * v.x; acc1 += p * v.y;
    }
  }
  __syncthreads();
  if (CONCAT){
    float inv = 1.0f / (s_run[h2] + 1e-16f);
    float2 o = make_float2(acc0 * inv, acc1 * inv);
    *reinterpret_cast<float2*>(&out[(size_t)n * 512 + 2 * tid]) = o;
  } else {
    float inv = 0.125f / (s_run[h2] + 1e-16f);
    float* fbuf = &sp[0][0];              // reuse 512+ floats of LDS
    fbuf[2 * tid]     = acc0 * inv;
    fbuf[2 * tid + 1] = acc1 * inv;
    __syncthreads();
    if (tid < 64){
      float s = 0.f;
      #pragma unroll
      for (int hh = 0; hh < 8; ++hh) s += fbuf[hh * 64 + tid];
      out[(size_t)n * 64 + tid] = s + bias[tid];
    }
  }
}

// ---------------- host launch ----------------
extern "C" void kernel_launch(void* const* d_in, const int* in_sizes, int n_in,
                              void* d_out, int out_size, void* d_ws, size_t ws_size,
                              hipStream_t stream){
  const float* x   = (const float*)d_in[0];
  const int*   ei  = (const int*)  d_in[1];
  const float* W1  = (const float*)d_in[2];
  const float* as1 = (const float*)d_in[3];
  const float* ad1 = (const float*)d_in[4];
  const float* b1  = (const float*)d_in[5];
  const float* W2  = (const float*)d_in[6];
  const float* as2 = (const float*)d_in[7];
  const float* ad2 = (const float*)d_in[8];
  const float* b2  = (const float*)d_in[9];
  float* out = (float*)d_out;
  const int E = in_sizes[1] / 2;
  const int EN = E + NNODE;

  // workspace carve-up (~191 MB)
  char* w = (char*)d_ws;
  bf16_t* Ahi = (bf16_t*)w; w += (size_t)NNODE * HH * 2;
  bf16_t* Alo = (bf16_t*)w; w += (size_t)NNODE * HH * 2;
  float* xp   = (float*)w;  w += (size_t)NNODE * HH * 4;
  float* o1   = (float*)w;  w += (size_t)NNODE * HH * 4;
  bf16_t* Wt1hi = (bf16_t*)w; w += (size_t)512 * 512 * 2;
  bf16_t* Wt1lo = (bf16_t*)w; w += (size_t)512 * 512 * 2;
  bf16_t* Wt2hi = (bf16_t*)w; w += (size_t)512 * 512 * 2;
  bf16_t* Wt2lo = (bf16_t*)w; w += (size_t)512 * 512 * 2;
  float* a_s  = (float*)w; w += (size_t)NNODE * HEADS * 4;
  float* a_d  = (float*)w; w += (size_t)NNODE * HEADS * 4;
  int* deg     = (int*)w; w += (size_t)NNODE * 4;
  int* row_ptr = (int*)w; w += (size_t)(NNODE + 1) * 4;
  int* cur     = (int*)w; w += (size_t)NNODE * 4;
  int* col     = (int*)w; w += (size_t)EN * 4;

  // partitionable split of key(42)=(0,42): child j = tf(key,(0,j))
  unsigned k1a, k1b, k2a, k2b;
  tf2x32(0u, 42u, 0u, 0u, k1a, k1b);
  tf2x32(0u, 42u, 0u, 1u, k2a, k2b);

  const int total4 = NNODE * HH / 4;
  const int gemm_grid = ((NNODE + 127) / 128) * 4;

  // ---- one-time prep ----
  splitW_kernel<<<1024, 256, 0, stream>>>(W1, Wt1hi, Wt1lo);
  splitW_kernel<<<1024, 256, 0, stream>>>(W2, Wt2hi, Wt2lo);
  init_deg_kernel<<<(NNODE + 255) / 256, 256, 0, stream>>>(deg);
  count_deg_kernel<<<(E + 255) / 256, 256, 0, stream>>>(ei, deg, E);
  scan_kernel<<<1, 1024, 0, stream>>>(deg, row_ptr, cur);
  scatter_kernel<<<(EN + 255) / 256, 256, 0, stream>>>(ei, cur, col, E);

  // ---- layer 1 ----
  dropelu_split_kernel<<<(total4 + 255) / 256, 256, 0, stream>>>(x, nullptr, Ahi, Alo, k1a, k1b, total4, HH);
  gemm_mfma_kernel<<<gemm_grid, 256, 0, stream>>>(Ahi, Alo, Wt1hi, Wt1lo, xp, NNODE);
  attn_coef_kernel<<<(NNODE * HEADS + 3) / 4, 256, 0, stream>>>(xp, as1, ad1, a_s, a_d);
  gat_aggregate2_kernel<true><<<NNODE, 256, 0, stream>>>(row_ptr, col, a_s, a_d, xp, nullptr, o1);

  // ---- layer 2 ----
  dropelu_split_kernel<<<(total4 + 255) / 256, 256, 0, stream>>>(o1, b1, Ahi, Alo, k2a, k2b, total4, HH);
  gemm_mfma_kernel<<<gemm_grid, 256, 0, stream>>>(Ahi, Alo, Wt2hi, Wt2lo, xp, NNODE);
  attn_coef_kernel<<<(NNODE * HEADS + 3) / 4, 256, 0, stream>>>(xp, as2, ad2, a_s, a_d);
  gat_aggregate2_kernel<false><<<NNODE, 256, 0, stream>>>(row_ptr, col, a_s, a_d, xp, b2, out);
}

// Round 10
// 616.031 us; speedup vs baseline: 4.6835x; 1.2463x over previous
//
#include <hip/hip_runtime.h>
#include <math.h>

#define HD __host__ __device__

static constexpr int NNODE = 30000;   // nodes
static constexpr int HH    = 512;     // HEADS*HID = hidden width (both layers)
static constexpr int HEADS = 8;
static constexpr int CD    = 64;      // channels per head
static constexpr float SLOPE = 0.2f;
static constexpr int TILE = 128;      // edges per aggregation tile

typedef unsigned short bf16_t;
typedef __attribute__((ext_vector_type(8))) short short8;
typedef __attribute__((ext_vector_type(4))) float f32x4;
struct alignas(8) US4 { unsigned short x, y, z, w; };

__device__ inline float bf2f(unsigned short h){ return __uint_as_float((unsigned)h << 16); }
__device__ inline unsigned short f2bf_rne(float f){
  unsigned u = __float_as_uint(f);
  unsigned r = (u + 0x7FFFu + ((u >> 16) & 1u)) >> 16;
  return (unsigned short)r;
}

// ---------------- threefry2x32 (exact JAX semantics) ----------------
HD inline unsigned rotl32(unsigned v, int s){ return (v<<s) | (v>>(32-s)); }

HD inline void tf2x32(unsigned k0, unsigned k1, unsigned c0, unsigned c1,
                      unsigned &o0, unsigned &o1){
  unsigned ks2 = k0 ^ k1 ^ 0x1BD11BDAu;
  unsigned x0 = c0 + k0, x1 = c1 + k1;
  x0+=x1; x1=rotl32(x1,13); x1^=x0;
  x0+=x1; x1=rotl32(x1,15); x1^=x0;
  x0+=x1; x1=rotl32(x1,26); x1^=x0;
  x0+=x1; x1=rotl32(x1, 6); x1^=x0;
  x0 += k1; x1 += ks2 + 1u;
  x0+=x1; x1=rotl32(x1,17); x1^=x0;
  x0+=x1; x1=rotl32(x1,29); x1^=x0;
  x0+=x1; x1=rotl32(x1,16); x1^=x0;
  x0+=x1; x1=rotl32(x1,24); x1^=x0;
  x0 += ks2; x1 += k0 + 2u;
  x0+=x1; x1=rotl32(x1,13); x1^=x0;
  x0+=x1; x1=rotl32(x1,15); x1^=x0;
  x0+=x1; x1=rotl32(x1,26); x1^=x0;
  x0+=x1; x1=rotl32(x1, 6); x1^=x0;
  x0 += k0; x1 += k1 + 3u;
  x0+=x1; x1=rotl32(x1,17); x1^=x0;
  x0+=x1; x1=rotl32(x1,29); x1^=x0;
  x0+=x1; x1=rotl32(x1,16); x1^=x0;
  x0+=x1; x1=rotl32(x1,24); x1^=x0;
  x0 += k1; x1 += ks2 + 4u;
  x0+=x1; x1=rotl32(x1,13); x1^=x0;
  x0+=x1; x1=rotl32(x1,15); x1^=x0;
  x0+=x1; x1=rotl32(x1,26); x1^=x0;
  x0+=x1; x1=rotl32(x1, 6); x1^=x0;
  x0 += ks2; x1 += k0 + 5u;
  o0 = x0; o1 = x1;
}

// ---------------- dropout + (bias) + ELU -> bf16 hi/lo split, x4 per thread ----------------
__global__ void dropelu_split_kernel(const float* __restrict__ in, const float* __restrict__ bias,
                                     bf16_t* __restrict__ hi, bf16_t* __restrict__ lo,
                                     unsigned key0, unsigned key1, int total4, int width){
  int i = blockIdx.x * blockDim.x + threadIdx.x;
  if (i >= total4) return;
  int e0 = i * 4;
  float4 v4 = *reinterpret_cast<const float4*>(&in[e0]);
  float vv[4] = {v4.x, v4.y, v4.z, v4.w};
  if (bias){
    float4 b4 = *reinterpret_cast<const float4*>(&bias[e0 % width]);
    vv[0]+=b4.x; vv[1]+=b4.y; vv[2]+=b4.z; vv[3]+=b4.w;
  }
  US4 h4, l4;
  unsigned short* hp = &h4.x; unsigned short* lp = &l4.x;
  #pragma unroll
  for (int j = 0; j < 4; ++j){
    unsigned o0, o1;
    tf2x32(key0, key1, 0u, (unsigned)(e0 + j), o0, o1);
    unsigned bits = o0 ^ o1;
    float u = __uint_as_float((bits >> 9) | 0x3f800000u) - 1.0f;  // [0,1)
    float v = vv[j];
    v = (u < 0.8f) ? (v * 1.25f) : 0.0f;         // dropout keep-prob 0.8
    v = (v > 0.0f) ? v : expm1f(v);              // ELU
    unsigned short hh = f2bf_rne(v);
    hp[j] = hh;
    lp[j] = f2bf_rne(v - bf2f(hh));
  }
  *reinterpret_cast<US4*>(&hi[e0]) = h4;
  *reinterpret_cast<US4*>(&lo[e0]) = l4;
}

// ---------------- W1,W2 [512x512] -> transposed bf16 hi/lo splits (single launch) ----------------
__global__ void splitW2_kernel(const float* __restrict__ W1, const float* __restrict__ W2,
                               bf16_t* __restrict__ Wt1hi, bf16_t* __restrict__ Wt1lo,
                               bf16_t* __restrict__ Wt2hi, bf16_t* __restrict__ Wt2lo){
  int idx = blockIdx.x * blockDim.x + threadIdx.x;
  int which = idx >> 18;                 // 512*512 = 2^18
  int r = idx & ((1 << 18) - 1);
  int j = r >> 9, k = r & 511;
  const float* W = which ? W2 : W1;
  bf16_t* Whi = which ? Wt2hi : Wt1hi;
  bf16_t* Wlo = which ? Wt2lo : Wt1lo;
  float v = W[k * 512 + j];
  unsigned short hh = f2bf_rne(v);
  Whi[r] = hh;
  Wlo[r] = f2bf_rne(v - bf2f(hh));
}

// ---------------- MFMA GEMM + fused attn-coef epilogue ----------------
// C = (Ahi+Alo)@(Bhi+Blo) (bf16x3, f32 acc); writes xp as bf16; computes
// a_s/a_d for heads 2*bx+wc directly from f32 accumulators (head-complete per wave).
#define LSTR 40
__global__ __launch_bounds__(256) void gemm_mfma_fused_kernel(
    const bf16_t* __restrict__ Ahi, const bf16_t* __restrict__ Alo,
    const bf16_t* __restrict__ Bthi, const bf16_t* __restrict__ Btlo,
    const float* __restrict__ att_src, const float* __restrict__ att_dst,
    bf16_t* __restrict__ xpb, float* __restrict__ a_s, float* __restrict__ a_d, int M){
  __shared__ bf16_t lAhi[128][LSTR], lAlo[128][LSTR], lBhi[128][LSTR], lBlo[128][LSTR];
  int t  = threadIdx.x;
  int bx = blockIdx.x & 3;
  int by = blockIdx.x >> 2;
  int row0 = by * 128, col0 = bx * 128;
  int lane = t & 63, wid = t >> 6;
  int wr = wid >> 1, wc = wid & 1;
  f32x4 acc[4][4] = {};
  int srow  = t >> 1;
  int skoff = (t & 1) * 16;
  int frow = lane & 15, fk = (lane >> 4) * 8;
  for (int k0 = 0; k0 < 512; k0 += 32){
    {
      const bf16_t* pa = &Ahi[(size_t)(row0 + srow) * 512 + k0 + skoff];
      *reinterpret_cast<short8*>(&lAhi[srow][skoff])     = *reinterpret_cast<const short8*>(pa);
      *reinterpret_cast<short8*>(&lAhi[srow][skoff + 8]) = *reinterpret_cast<const short8*>(pa + 8);
      const bf16_t* pl = &Alo[(size_t)(row0 + srow) * 512 + k0 + skoff];
      *reinterpret_cast<short8*>(&lAlo[srow][skoff])     = *reinterpret_cast<const short8*>(pl);
      *reinterpret_cast<short8*>(&lAlo[srow][skoff + 8]) = *reinterpret_cast<const short8*>(pl + 8);
      const bf16_t* pb = &Bthi[(size_t)(col0 + srow) * 512 + k0 + skoff];
      *reinterpret_cast<short8*>(&lBhi[srow][skoff])     = *reinterpret_cast<const short8*>(pb);
      *reinterpret_cast<short8*>(&lBhi[srow][skoff + 8]) = *reinterpret_cast<const short8*>(pb + 8);
      const bf16_t* pc = &Btlo[(size_t)(col0 + srow) * 512 + k0 + skoff];
      *reinterpret_cast<short8*>(&lBlo[srow][skoff])     = *reinterpret_cast<const short8*>(pc);
      *reinterpret_cast<short8*>(&lBlo[srow][skoff + 8]) = *reinterpret_cast<const short8*>(pc + 8);
    }
    __syncthreads();
    short8 fahi[4], falo[4], fbhi[4], fblo[4];
    #pragma unroll
    for (int m = 0; m < 4; ++m){
      fahi[m] = *reinterpret_cast<const short8*>(&lAhi[wr*64 + m*16 + frow][fk]);
      falo[m] = *reinterpret_cast<const short8*>(&lAlo[wr*64 + m*16 + frow][fk]);
    }
    #pragma unroll
    for (int n = 0; n < 4; ++n){
      fbhi[n] = *reinterpret_cast<const short8*>(&lBhi[wc*64 + n*16 + frow][fk]);
      fblo[n] = *reinterpret_cast<const short8*>(&lBlo[wc*64 + n*16 + frow][fk]);
    }
    #pragma unroll
    for (int m = 0; m < 4; ++m)
      #pragma unroll
      for (int n = 0; n < 4; ++n){
        acc[m][n] = __builtin_amdgcn_mfma_f32_16x16x32_bf16(fahi[m], fbhi[n], acc[m][n], 0, 0, 0);
        acc[m][n] = __builtin_amdgcn_mfma_f32_16x16x32_bf16(fahi[m], fblo[n], acc[m][n], 0, 0, 0);
        acc[m][n] = __builtin_amdgcn_mfma_f32_16x16x32_bf16(falo[m], fbhi[n], acc[m][n], 0, 0, 0);
      }
    __syncthreads();
  }
  // ---- write xp (bf16) ----
  int rbase = row0 + wr * 64 + (lane >> 4) * 4;
  int cbase = col0 + wc * 64 + (lane & 15);
  #pragma unroll
  for (int m = 0; m < 4; ++m)
    #pragma unroll
    for (int n = 0; n < 4; ++n)
      #pragma unroll
      for (int r = 0; r < 4; ++r){
        int gr = rbase + m * 16 + r;
        if (gr < M) xpb[(size_t)gr * 512 + cbase + n * 16] = f2bf_rne(acc[m][n][r]);
      }
  // ---- fused attn coefficients for head hh = 2*bx + wc (this wave owns its 64 cols) ----
  int hh = 2 * bx + wc;
  float as_c[4], ad_c[4];
  #pragma unroll
  for (int n = 0; n < 4; ++n){
    as_c[n] = att_src[hh * 64 + n * 16 + (lane & 15)];
    ad_c[n] = att_dst[hh * 64 + n * 16 + (lane & 15)];
  }
  #pragma unroll
  for (int m = 0; m < 4; ++m)
    #pragma unroll
    for (int r = 0; r < 4; ++r){
      float ps = 0.f, pd = 0.f;
      #pragma unroll
      for (int n = 0; n < 4; ++n){
        ps += acc[m][n][r] * as_c[n];
        pd += acc[m][n][r] * ad_c[n];
      }
      #pragma unroll
      for (int off = 1; off < 16; off <<= 1){
        ps += __shfl_xor(ps, off, 64);
        pd += __shfl_xor(pd, off, 64);
      }
      int row = row0 + wr * 64 + m * 16 + (lane >> 4) * 4 + r;
      if ((lane & 15) == 0 && row < M){
        a_s[row * 8 + hh] = ps;
        a_d[row * 8 + hh] = pd;
      }
    }
}

// ---------------- CSR build ----------------
__global__ void init_deg_kernel(int* __restrict__ deg){
  int i = blockIdx.x * blockDim.x + threadIdx.x;
  if (i < NNODE) deg[i] = 1;                     // self loop
}

__global__ void count_deg_kernel(const int* __restrict__ ei, int* __restrict__ deg, int E){
  int t = blockIdx.x * blockDim.x + threadIdx.x;
  if (t < E) atomicAdd(&deg[ei[E + t]], 1);
}

__global__ __launch_bounds__(1024) void scan_kernel(const int* __restrict__ deg,
                                                    int* __restrict__ row_ptr,
                                                    int* __restrict__ cur){
  __shared__ int sums[1024];
  int t = threadIdx.x;
  const int PER = (NNODE + 1023) / 1024;
  int base = t * PER;
  int s = 0;
  for (int i = 0; i < PER; ++i){ int idx = base + i; if (idx < NNODE) s += deg[idx]; }
  sums[t] = s;
  __syncthreads();
  for (int off = 1; off < 1024; off <<= 1){
    int v = (t >= off) ? sums[t - off] : 0;
    __syncthreads();
    sums[t] += v;
    __syncthreads();
  }
  int run = (t == 0) ? 0 : sums[t - 1];
  for (int i = 0; i < PER; ++i){
    int idx = base + i;
    if (idx < NNODE){ row_ptr[idx] = run; cur[idx] = run; run += deg[idx]; }
  }
  if (t == 1023) row_ptr[NNODE] = sums[1023];
}

__global__ void scatter_kernel(const int* __restrict__ ei, int* __restrict__ cur,
                               int* __restrict__ col, int E){
  int t = blockIdx.x * blockDim.x + threadIdx.x;
  int total = E + NNODE;
  if (t >= total) return;
  int src, dst;
  if (t < E){ src = ei[t]; dst = ei[E + t]; }
  else      { src = t - E; dst = t - E; }
  int pos = atomicAdd(&cur[dst], 1);
  col[pos] = src;
}

// ---------------- block-per-dst fused softmax + aggregate v3 ----------------
// bf16 xp; accumulate phase: 2 edge-groups x (128 threads x 4 channels).
template <bool CONCAT>
__global__ __launch_bounds__(256) void gat_aggregate3_kernel(
    const int* __restrict__ row_ptr, const int* __restrict__ col,
    const float* __restrict__ a_s, const float* __restrict__ a_d,
    const bf16_t* __restrict__ xpb, const float* __restrict__ bias,
    float* __restrict__ out){
  int n   = blockIdx.x;
  int tid = threadIdx.x;
  int lane = tid & 63, wslot = tid >> 6;
  int h  = tid & 7;          // score-phase head
  int g  = tid >> 7;         // edge group (0/1)
  int local = tid & 127;     // channel-group index
  int c0 = local * 4;        // 4 channels per thread
  int h2 = local >> 4;       // head of owned channels
  __shared__ int   scol[TILE];
  __shared__ float sp[TILE][8];
  __shared__ float red[32];
  __shared__ float m_run[8], s_run[8], nm[8], fr[8];
  __shared__ float xacc[512];
  int start = row_ptr[n], end = row_ptr[n + 1];
  int deg = end - start;
  if (tid < 8){ m_run[tid] = -INFINITY; s_run[tid] = 0.f; }
  float adh = a_d[n * 8 + h];
  float a0 = 0.f, a1 = 0.f, a2 = 0.f, a3 = 0.f;
  for (int base = 0; base < deg; base += TILE){
    int len = min(TILE, deg - base);
    __syncthreads();
    if (tid < TILE) scol[tid] = (tid < len) ? col[start + base + tid] : 0;
    __syncthreads();
    // ---- scores + per-head tile max ----
    float mpart = -INFINITY;
    #pragma unroll
    for (int k = 0; k < TILE * 8 / 256; ++k){
      int j = (tid >> 3) + k * 32;
      float e = -INFINITY;
      if (j < len){
        int src = scol[j];
        e = a_s[src * 8 + h] + adh;
        e = (e >= 0.f) ? e : SLOPE * e;
      }
      sp[j][h] = e;
      mpart = fmaxf(mpart, e);
    }
    #pragma unroll
    for (int off = 8; off < 64; off <<= 1) mpart = fmaxf(mpart, __shfl_xor(mpart, off, 64));
    if (lane < 8) red[wslot * 8 + lane] = mpart;
    __syncthreads();
    if (tid < 8){
      float tm = fmaxf(fmaxf(red[tid], red[8 + tid]), fmaxf(red[16 + tid], red[24 + tid]));
      float om = m_run[tid];
      float nmv = fmaxf(om, tm);
      nm[tid] = nmv;
      fr[tid] = expf(om - nmv);
      m_run[tid] = nmv;
    }
    __syncthreads();
    // ---- p = exp(e - m) + per-head tile sum ----
    float nmh = nm[h];
    float spart = 0.f;
    #pragma unroll
    for (int k = 0; k < TILE * 8 / 256; ++k){
      int j = (tid >> 3) + k * 32;
      float p = expf(sp[j][h] - nmh);
      sp[j][h] = p;
      spart += p;
    }
    #pragma unroll
    for (int off = 8; off < 64; off <<= 1) spart += __shfl_xor(spart, off, 64);
    __syncthreads();
    if (lane < 8) red[wslot * 8 + lane] = spart;
    __syncthreads();
    if (tid < 8){
      float ts = red[tid] + red[8 + tid] + red[16 + tid] + red[24 + tid];
      s_run[tid] = s_run[tid] * fr[tid] + ts;
    }
    // ---- rescale + accumulate (group g takes edges j = g, g+2, ...) ----
    float f = fr[h2];
    a0 *= f; a1 *= f; a2 *= f; a3 *= f;
    for (int j = g; j < len; j += 2){
      float p = sp[j][h2];
      int src = scol[j];
      US4 v = *reinterpret_cast<const US4*>(&xpb[(size_t)src * 512 + c0]);
      a0 += p * bf2f(v.x); a1 += p * bf2f(v.y);
      a2 += p * bf2f(v.z); a3 += p * bf2f(v.w);
    }
  }
  __syncthreads();
  if (g == 1){
    xacc[c0] = a0; xacc[c0+1] = a1; xacc[c0+2] = a2; xacc[c0+3] = a3;
  }
  __syncthreads();
  if (g == 0){
    a0 += xacc[c0]; a1 += xacc[c0+1]; a2 += xacc[c0+2]; a3 += xacc[c0+3];
    if (CONCAT){
      float inv = 1.0f / (s_run[h2] + 1e-16f);
      float4 o = make_float4(a0*inv, a1*inv, a2*inv, a3*inv);
      *reinterpret_cast<float4*>(&out[(size_t)n * 512 + c0]) = o;
    } else {
      float inv = 0.125f / (s_run[h2] + 1e-16f);
      xacc[c0] = a0*inv; xacc[c0+1] = a1*inv; xacc[c0+2] = a2*inv; xacc[c0+3] = a3*inv;
    }
  }
  if (!CONCAT){
    __syncthreads();
    if (tid < 64){
      float s = 0.f;
      #pragma unroll
      for (int hh = 0; hh < 8; ++hh) s += xacc[hh * 64 + tid];
      out[(size_t)n * 64 + tid] = s + bias[tid];
    }
  }
}

// ---------------- host launch ----------------
extern "C" void kernel_launch(void* const* d_in, const int* in_sizes, int n_in,
                              void* d_out, int out_size, void* d_ws, size_t ws_size,
                              hipStream_t stream){
  const float* x   = (const float*)d_in[0];
  const int*   ei  = (const int*)  d_in[1];
  const float* W1  = (const float*)d_in[2];
  const float* as1 = (const float*)d_in[3];
  const float* ad1 = (const float*)d_in[4];
  const float* b1  = (const float*)d_in[5];
  const float* W2  = (const float*)d_in[6];
  const float* as2 = (const float*)d_in[7];
  const float* ad2 = (const float*)d_in[8];
  const float* b2  = (const float*)d_in[9];
  float* out = (float*)d_out;
  const int E = in_sizes[1] / 2;
  const int EN = E + NNODE;

  // workspace carve-up (~165 MB)
  char* w = (char*)d_ws;
  bf16_t* Ahi = (bf16_t*)w; w += (size_t)NNODE * HH * 2;
  bf16_t* Alo = (bf16_t*)w; w += (size_t)NNODE * HH * 2;
  bf16_t* xpb = (bf16_t*)w; w += (size_t)NNODE * HH * 2;     // bf16 xp
  float* o1   = (float*)w;  w += (size_t)NNODE * HH * 4;
  bf16_t* Wt1hi = (bf16_t*)w; w += (size_t)512 * 512 * 2;
  bf16_t* Wt1lo = (bf16_t*)w; w += (size_t)512 * 512 * 2;
  bf16_t* Wt2hi = (bf16_t*)w; w += (size_t)512 * 512 * 2;
  bf16_t* Wt2lo = (bf16_t*)w; w += (size_t)512 * 512 * 2;
  float* a_s  = (float*)w; w += (size_t)NNODE * HEADS * 4;
  float* a_d  = (float*)w; w += (size_t)NNODE * HEADS * 4;
  int* deg     = (int*)w; w += (size_t)NNODE * 4;
  int* row_ptr = (int*)w; w += (size_t)(NNODE + 1) * 4;
  int* cur     = (int*)w; w += (size_t)NNODE * 4;
  int* col     = (int*)w; w += (size_t)EN * 4;

  // partitionable split of key(42)=(0,42): child j = tf(key,(0,j))
  unsigned k1a, k1b, k2a, k2b;
  tf2x32(0u, 42u, 0u, 0u, k1a, k1b);
  tf2x32(0u, 42u, 0u, 1u, k2a, k2b);

  const int total4 = NNODE * HH / 4;
  const int gemm_grid = ((NNODE + 127) / 128) * 4;

  // ---- one-time prep ----
  splitW2_kernel<<<2048, 256, 0, stream>>>(W1, W2, Wt1hi, Wt1lo, Wt2hi, Wt2lo);
  init_deg_kernel<<<(NNODE + 255) / 256, 256, 0, stream>>>(deg);
  count_deg_kernel<<<(E + 255) / 256, 256, 0, stream>>>(ei, deg, E);
  scan_kernel<<<1, 1024, 0, stream>>>(deg, row_ptr, cur);
  scatter_kernel<<<(EN + 255) / 256, 256, 0, stream>>>(ei, cur, col, E);

  // ---- layer 1 ----
  dropelu_split_kernel<<<(total4 + 255) / 256, 256, 0, stream>>>(x, nullptr, Ahi, Alo, k1a, k1b, total4, HH);
  gemm_mfma_fused_kernel<<<gemm_grid, 256, 0, stream>>>(Ahi, Alo, Wt1hi, Wt1lo, as1, ad1, xpb, a_s, a_d, NNODE);
  gat_aggregate3_kernel<true><<<NNODE, 256, 0, stream>>>(row_ptr, col, a_s, a_d, xpb, nullptr, o1);

  // ---- layer 2 ----
  dropelu_split_kernel<<<(total4 + 255) / 256, 256, 0, stream>>>(o1, b1, Ahi, Alo, k2a, k2b, total4, HH);
  gemm_mfma_fused_kernel<<<gemm_grid, 256, 0, stream>>>(Ahi, Alo, Wt2hi, Wt2lo, as2, ad2, xpb, a_s, a_d, NNODE);
  gat_aggregate3_kernel<false><<<NNODE, 256, 0, stream>>>(row_ptr, col, a_s, a_d, xpb, b2, out);
}